// Round 6
// baseline (146.256 us; speedup 1.0000x reference)
//
#include <hip/hip_runtime.h>
#include <hip/hip_bf16.h>
#include <stdint.h>

#define DEV static __device__ __forceinline__

typedef __attribute__((ext_vector_type(8))) short   s16x8;
typedef __attribute__((ext_vector_type(4))) short   s16x4;
typedef __attribute__((ext_vector_type(8))) __bf16  bf16x8;
typedef __attribute__((ext_vector_type(4))) float   f32x4;

DEV short f2b(float f){           // round-to-nearest-even f32 -> bf16
  union{float f; uint32_t i;} x; x.f = f;
  uint32_t r = x.i + 0x7FFFu + ((x.i >> 16) & 1u);
  return (short)(r >> 16);
}
DEV bf16x8 as_bf(s16x8 v){ return __builtin_bit_cast(bf16x8, v); }
DEV float fexp2(float x){ return __builtin_amdgcn_exp2f(x); }   // v_exp_f32: 2^x
DEV f32x4 mf(s16x8 a, s16x8 b, f32x4 c){
  return __builtin_amdgcn_mfma_f32_16x16x32_bf16(as_bf(a), as_bf(b), c, 0, 0, 0);
}

DEV void gload_lds16(const void* g, void* l){
  __builtin_amdgcn_global_load_lds((const __attribute__((address_space(1))) void*)g,
                                   (__attribute__((address_space(3))) void*)l, 16, 0, 0);
}

// ---------------- fused convert f32 -> bf16 for query/key_in/value ----------------
__global__ __launch_bounds__(256) void k_conv3(const float* __restrict__ q,
                                               const float* __restrict__ k,
                                               const float* __restrict__ v,
                                               short* __restrict__ out){
  int z = blockIdx.z;
  const float* in = (z == 0) ? q : (z == 1) ? k : v;
  int i = (blockIdx.x * 256 + threadIdx.x) * 4;
  float4 val = *(const float4*)(in + i);
  short o[4] = { f2b(val.x), f2b(val.y), f2b(val.z), f2b(val.w) };
  *(uint2*)(out + (size_t)z * 4194304 + i) = *(uint2*)o;
}

// ------------- fused weight transpose+convert: 4x w[512][512] f32 -> wt[n][k] bf16 -------------
__global__ __launch_bounds__(256) void k_wt4(const float* __restrict__ w0,
                                             const float* __restrict__ w1,
                                             const float* __restrict__ w2,
                                             const float* __restrict__ w3,
                                             short* __restrict__ wt){
  __shared__ float tile[32][33];
  int z = blockIdx.z;
  const float* w = (z == 0) ? w0 : (z == 1) ? w1 : (z == 2) ? w2 : w3;
  short* o = wt + (size_t)z * 262144;
  int bx = blockIdx.x * 32, by = blockIdx.y * 32;   // bx: n-block, by: k-block
  int tx = threadIdx.x, ty = threadIdx.y;           // (32, 8)
  for (int j = 0; j < 32; j += 8)
    tile[ty + j][tx] = w[(size_t)(by + ty + j) * 512 + bx + tx];
  __syncthreads();
  for (int j = 0; j < 32; j += 8)
    o[(size_t)(bx + ty + j) * 512 + by + tx] = f2b(tile[tx][ty + j]);
}

// ---------------- RoPE cos/sin table: tab[s][j][{cos,sin}], s<1024, j<32 ----------------
__global__ __launch_bounds__(256) void k_table(float* __restrict__ tab){
  int idx = blockIdx.x * 256 + threadIdx.x;   // 32768
  int s = idx >> 5, j = idx & 31;
  float inv = __expf(-(float)j * (1.0f / 32.0f) * logf(10000.0f));
  float ang = (float)s * inv;
  tab[idx * 2 + 0] = cosf(ang);
  tab[idx * 2 + 1] = sinf(ang);
}

// ---------------- fused QKV GEMM + RoPE/layout epilogues ----------------
__global__ __launch_bounds__(256) void k_qkv(const short* __restrict__ Xq,
                                             const short* __restrict__ Xk,
                                             const short* __restrict__ Xv,
                                             const short* __restrict__ Wcat,
                                             const float* __restrict__ tab,
                                             short* __restrict__ Qa,
                                             short* __restrict__ Ka,
                                             short* __restrict__ Vt){
  __shared__ __align__(16) short Al[128 * 32];
  __shared__ __align__(16) short Bl[128 * 32];
  const int t = threadIdx.x;
  const int w = t >> 6, lane = t & 63, fr = lane & 15, fg = lane >> 4;
  const int sel = blockIdx.y >> 2;
  const short* X = (sel == 0) ? Xq : (sel == 1) ? Xk : Xv;
  const int bm = blockIdx.x * 128, bn = blockIdx.y * 128;
  const int wm = (w >> 1) * 64, wn = (w & 1) * 64;
  const int r8 = t >> 2, c8 = (t & 3) * 8;
  f32x4 acc[4][4] = {};
  for (int k0 = 0; k0 < 512; k0 += 32){
    __syncthreads();
#pragma unroll
    for (int j = 0; j < 2; j++){
      const short* ga = X    + (size_t)(bm + j * 64 + r8) * 512 + (k0 + c8);
      const short* gb = Wcat + (size_t)(bn + j * 64 + r8) * 512 + (k0 + c8);
      gload_lds16(ga, &Al[j * 2048 + w * 512]);
      gload_lds16(gb, &Bl[j * 2048 + w * 512]);
    }
    __syncthreads();
    s16x8 af[4], bv[4];
#pragma unroll
    for (int f = 0; f < 4; f++){
      af[f] = *(const s16x8*)(&Al[(wm + f * 16 + fr) * 32 + fg * 8]);
      bv[f] = *(const s16x8*)(&Bl[(wn + f * 16 + fr) * 32 + fg * 8]);
    }
#pragma unroll
    for (int i = 0; i < 4; i++)
#pragma unroll
      for (int jj = 0; jj < 4; jj++)
        acc[i][jj] = __builtin_amdgcn_mfma_f32_16x16x32_bf16(as_bf(af[i]), as_bf(bv[jj]),
                                                             acc[i][jj], 0, 0, 0);
  }
  const int row0 = bm + wm + fg * 4;         // + i*16 + r
  const int b = row0 >> 10;
  const int s_base = row0 & 1023;
  const int hh = (((blockIdx.y & 3) * 128) + wn) >> 6;   // head 0..7
  if (sel < 2){
    const float scale = (sel == 0) ? 0.125f * 1.44269504f : 1.0f;
    short* out = (sel == 0) ? Qa : Ka;
#pragma unroll
    for (int i = 0; i < 4; i++)
#pragma unroll
      for (int jj = 0; jj < 2; jj++){
        int d = jj * 16 + fr;                // 0..31
#pragma unroll
        for (int r = 0; r < 4; r++){
          int s = s_base + i * 16 + r;
          float2 cs = *(const float2*)(tab + (size_t)(s * 32 + d) * 2);
          float x1 = acc[i][jj][r], x2 = acc[i][jj + 2][r];
          size_t ob = ((size_t)((b * 8 + hh) * 1024 + s)) * 64 + d;
          out[ob]      = f2b((x1 * cs.x - x2 * cs.y) * scale);
          out[ob + 32] = f2b((x2 * cs.x + x1 * cs.y) * scale);
        }
      }
  } else {
#pragma unroll
    for (int i = 0; i < 4; i++)
#pragma unroll
      for (int jj = 0; jj < 4; jj++){
        int d = jj * 16 + fr;
        s16x4 pk;
#pragma unroll
        for (int r = 0; r < 4; r++) pk[r] = f2b(acc[i][jj][r]);
        size_t ob = ((size_t)((b * 8 + hh) * 64 + d)) * 1024 + s_base + i * 16;
        *(s16x4*)(Vt + ob) = pk;
      }
  }
}

// ---------------- causal flash attention: paired q-tiles + 2-way split-KV ----------------
// Block = 128 threads (2 waves) on pair (p, 63-p) of one bh.
// Wave w handles kv chunks kv0 = 64w, 64w+128, ... ; partials merged via LDS at the end.
// Q staged in LDS (pad-72 rows). Tiles processed sequentially to cap VGPRs (target <=128).
__global__ __launch_bounds__(128, 4) void k_attn(const short* __restrict__ Qb,
                                                 const short* __restrict__ Kb,
                                                 const short* __restrict__ Vt,
                                                 short* __restrict__ O){
  __shared__ __align__(16) short Ql[2][16][72];      // [tile(A=0,B=1)][row][d]
  __shared__ __align__(16) short Pl[2][2][16 * 72];  // [wave][tile] P buffers
  __shared__ float MOx[2][64][16];                   // wave w writes its NON-merged tile's O
  __shared__ float Lm[2][2][16];                     // [wave][tile][q] running max
  __shared__ float Ll[2][2][16];                     // [wave][tile][q] l
  const int gid = blockIdx.x;
  const int swz = (gid & 7) * 256 + (gid >> 3);      // XCD-contiguous bh chunks
  const int bh  = swz >> 5;                          // 0..63
  const int pr  = swz & 31;                          // 0..31
  const int qwA = pr * 16;
  const int qwB = (63 - pr) * 16;                    // >= 512
  const int t = threadIdx.x, w = t >> 6, lane = t & 63, fr = lane & 15, fg = lane >> 4;
  const short* Qp = Qb + (size_t)bh * 65536;
  const short* Kp = Kb + (size_t)bh * 65536;
  const short* Vp = Vt + (size_t)bh * 65536;

  // ---- stage Q (both tiles, 4 KB) ----
  {
    int row32 = t >> 2, tile = row32 >> 4, rr = row32 & 15, c16 = (t & 3) * 16;
    int grow = (tile ? qwB : qwA) + rr;
    s16x8 g0 = *(const s16x8*)(Qp + (size_t)grow * 64 + c16);
    s16x8 g1 = *(const s16x8*)(Qp + (size_t)grow * 64 + c16 + 8);
    *(s16x8*)(&Ql[tile][rr][c16])     = g0;
    *(s16x8*)(&Ql[tile][rr][c16 + 8]) = g1;
  }
  __syncthreads();

  const short onev = (fr == 0) ? (short)0x3F80 : (short)0;
  s16x8 ones;
#pragma unroll
  for (int e = 0; e < 8; e++) ones[e] = onev;

  f32x4 oA[4] = {}, oB[4] = {};
  f32x4 oLA = {}, oLB = {};
  float mA = -1e30f, mB = -1e30f;
  short* PB = &Pl[w][1][0];
  short* PA = &Pl[w][0][0];

  for (int kv0 = 64 * w; kv0 <= qwB; kv0 += 128){
    const bool Aact = (kv0 <= qwA);
    f32x4 scB[4], scA[4];
    // ---- QK^T, d-half 0 ----
    {
      s16x8 kc[4];
#pragma unroll
      for (int f = 0; f < 4; f++)
        kc[f] = *(const s16x8*)(Kp + (size_t)(kv0 + f * 16 + fr) * 64 + fg * 8);
      s16x8 qx = *(const s16x8*)(&Ql[1][fr][fg * 8]);
#pragma unroll
      for (int f = 0; f < 4; f++){ f32x4 z = {}; scB[f] = mf(kc[f], qx, z); }
      if (Aact){
        qx = *(const s16x8*)(&Ql[0][fr][fg * 8]);
#pragma unroll
        for (int f = 0; f < 4; f++){ f32x4 z = {}; scA[f] = mf(kc[f], qx, z); }
      }
      // ---- d-half 1 (reuse kc) ----
#pragma unroll
      for (int f = 0; f < 4; f++)
        kc[f] = *(const s16x8*)(Kp + (size_t)(kv0 + f * 16 + fr) * 64 + 32 + fg * 8);
      qx = *(const s16x8*)(&Ql[1][fr][32 + fg * 8]);
#pragma unroll
      for (int f = 0; f < 4; f++) scB[f] = mf(kc[f], qx, scB[f]);
      if (Aact){
        qx = *(const s16x8*)(&Ql[0][fr][32 + fg * 8]);
#pragma unroll
        for (int f = 0; f < 4; f++) scA[f] = mf(kc[f], qx, scA[f]);
      }
    }
    // ---- causal masks (diagonal chunks only) ----
    if (kv0 + 63 > qwB){
      int q = qwB + fr;
#pragma unroll
      for (int f = 0; f < 4; f++)
#pragma unroll
        for (int r = 0; r < 4; r++){
          int kv = kv0 + f * 16 + fg * 4 + r;
          if (kv > q) scB[f][r] = -1e30f;
        }
    }
    if (Aact && kv0 + 63 > qwA){
      int q = qwA + fr;
#pragma unroll
      for (int f = 0; f < 4; f++)
#pragma unroll
        for (int r = 0; r < 4; r++){
          int kv = kv0 + f * 16 + fg * 4 + r;
          if (kv > q) scA[f][r] = -1e30f;
        }
    }
    // ---- softmax B (defer-max) ----
    {
      float tm0 = fmaxf(fmaxf(scB[0][0], scB[0][1]), fmaxf(scB[0][2], scB[0][3]));
      float tm1 = fmaxf(fmaxf(scB[1][0], scB[1][1]), fmaxf(scB[1][2], scB[1][3]));
      float tm2 = fmaxf(fmaxf(scB[2][0], scB[2][1]), fmaxf(scB[2][2], scB[2][3]));
      float tm3 = fmaxf(fmaxf(scB[3][0], scB[3][1]), fmaxf(scB[3][2], scB[3][3]));
      float tm = fmaxf(fmaxf(tm0, tm1), fmaxf(tm2, tm3));
      tm = fmaxf(tm, __shfl_xor(tm, 16, 64));
      tm = fmaxf(tm, __shfl_xor(tm, 32, 64));
      if (!__all(tm <= mB + 8.f)){
        float mn = fmaxf(mB, tm);
        float corr = fexp2(mB - mn);
        mB = mn;
        float cpv[4];
#pragma unroll
        for (int r = 0; r < 4; r++) cpv[r] = __shfl(corr, fg * 4 + r, 64);
#pragma unroll
        for (int jj = 0; jj < 4; jj++)
#pragma unroll
          for (int r = 0; r < 4; r++) oB[jj][r] *= cpv[r];
#pragma unroll
        for (int r = 0; r < 4; r++) oLB[r] *= cpv[r];
      }
#pragma unroll
      for (int f = 0; f < 4; f++){
        s16x4 pb;
#pragma unroll
        for (int r = 0; r < 4; r++) pb[r] = f2b(fexp2(scB[f][r] - mB));
        *(s16x4*)(&PB[fr * 72 + f * 16 + fg * 4]) = pb;
      }
    }
    // ---- softmax A (defer-max) ----
    if (Aact){
      float tm0 = fmaxf(fmaxf(scA[0][0], scA[0][1]), fmaxf(scA[0][2], scA[0][3]));
      float tm1 = fmaxf(fmaxf(scA[1][0], scA[1][1]), fmaxf(scA[1][2], scA[1][3]));
      float tm2 = fmaxf(fmaxf(scA[2][0], scA[2][1]), fmaxf(scA[2][2], scA[2][3]));
      float tm3 = fmaxf(fmaxf(scA[3][0], scA[3][1]), fmaxf(scA[3][2], scA[3][3]));
      float tm = fmaxf(fmaxf(tm0, tm1), fmaxf(tm2, tm3));
      tm = fmaxf(tm, __shfl_xor(tm, 16, 64));
      tm = fmaxf(tm, __shfl_xor(tm, 32, 64));
      if (!__all(tm <= mA + 8.f)){
        float mn = fmaxf(mA, tm);
        float corr = fexp2(mA - mn);
        mA = mn;
        float cpv[4];
#pragma unroll
        for (int r = 0; r < 4; r++) cpv[r] = __shfl(corr, fg * 4 + r, 64);
#pragma unroll
        for (int jj = 0; jj < 4; jj++)
#pragma unroll
          for (int r = 0; r < 4; r++) oA[jj][r] *= cpv[r];
#pragma unroll
        for (int r = 0; r < 4; r++) oLA[r] *= cpv[r];
      }
#pragma unroll
      for (int f = 0; f < 4; f++){
        s16x4 pb;
#pragma unroll
        for (int r = 0; r < 4; r++) pb[r] = f2b(fexp2(scA[f][r] - mA));
        *(s16x4*)(&PA[fr * 72 + f * 16 + fg * 4]) = pb;
      }
    }
    // ---- PV, kv-half 0 (shared V frags) ----
    {
      s16x8 vv[4];
#pragma unroll
      for (int jj = 0; jj < 4; jj++)
        vv[jj] = *(const s16x8*)(Vp + (size_t)(jj * 16 + fr) * 1024 + kv0 + fg * 8);
      s16x8 pb0 = *(const s16x8*)(&PB[fr * 72 + fg * 8]);
#pragma unroll
      for (int jj = 0; jj < 4; jj++) oB[jj] = mf(pb0, vv[jj], oB[jj]);
      oLB = mf(pb0, ones, oLB);
      if (Aact){
        s16x8 pa0 = *(const s16x8*)(&PA[fr * 72 + fg * 8]);
#pragma unroll
        for (int jj = 0; jj < 4; jj++) oA[jj] = mf(pa0, vv[jj], oA[jj]);
        oLA = mf(pa0, ones, oLA);
      }
      // ---- PV, kv-half 1 ----
#pragma unroll
      for (int jj = 0; jj < 4; jj++)
        vv[jj] = *(const s16x8*)(Vp + (size_t)(jj * 16 + fr) * 1024 + kv0 + 32 + fg * 8);
      s16x8 pb1 = *(const s16x8*)(&PB[fr * 72 + 32 + fg * 8]);
#pragma unroll
      for (int jj = 0; jj < 4; jj++) oB[jj] = mf(pb1, vv[jj], oB[jj]);
      oLB = mf(pb1, ones, oLB);
      if (Aact){
        s16x8 pa1 = *(const s16x8*)(&PA[fr * 72 + 32 + fg * 8]);
#pragma unroll
        for (int jj = 0; jj < 4; jj++) oA[jj] = mf(pa1, vv[jj], oA[jj]);
        oLA = mf(pa1, ones, oLA);
      }
    }
  }

  // ---- write partials: wave0's A (merged by wave1), wave1's B (merged by wave0) ----
#pragma unroll
  for (int jj = 0; jj < 4; jj++)
#pragma unroll
    for (int r = 0; r < 4; r++)
      MOx[w][lane][jj * 4 + r] = w ? oB[jj][r] : oA[jj][r];
  if (fg == 0){ Lm[w][0][fr] = mA; Lm[w][1][fr] = mB; }
  if (fr == 0){
#pragma unroll
    for (int r = 0; r < 4; r++){ Ll[w][0][fg * 4 + r] = oLA[r]; Ll[w][1][fg * 4 + r] = oLB[r]; }
  }
  __syncthreads();

  // ---- merge + output: wave0 -> tile B, wave1 -> tile A ----
  const int tmg = w ? 0 : 1;                 // tile this wave merges
  const int qw_ = w ? qwA : qwB;
  f32x4 own[4];
#pragma unroll
  for (int jj = 0; jj < 4; jj++) own[jj] = w ? oA[jj] : oB[jj];
  const int b = bh >> 3, h = bh & 7;
#pragma unroll
  for (int r = 0; r < 4; r++){
    int q = fg * 4 + r;
    float m0 = Lm[0][tmg][q], m1 = Lm[1][tmg][q];
    float ms = fmaxf(m0, m1);
    float c0 = fexp2(m0 - ms), c1 = fexp2(m1 - ms);
    float lst = Ll[0][tmg][q] * c0 + Ll[1][tmg][q] * c1;
    float cw = w ? c1 : c0;                  // own coefficient
    float cp = w ? c0 : c1;                  // partner coefficient
    float inv = 1.0f / lst;
    int qq = qw_ + q;
#pragma unroll
    for (int jj = 0; jj < 4; jj++){
      float val = (own[jj][r] * cw + MOx[1 - w][lane][jj * 4 + r] * cp) * inv;
      O[(size_t)(b * 1024 + qq) * 512 + h * 64 + jj * 16 + fr] = f2b(val);
    }
  }
}

// ---------------- final GEMM: f32 out ----------------
__global__ __launch_bounds__(256) void k_gemm_out(const short* __restrict__ X,
                                                  const short* __restrict__ Wt,
                                                  float* __restrict__ C){
  __shared__ __align__(16) short Al[128 * 32];
  __shared__ __align__(16) short Bl[128 * 32];
  const int t = threadIdx.x;
  const int w = t >> 6, lane = t & 63, fr = lane & 15, fg = lane >> 4;
  const int bm = blockIdx.x * 128, bn = blockIdx.y * 128;
  const int wm = (w >> 1) * 64, wn = (w & 1) * 64;
  const int r8 = t >> 2, c8 = (t & 3) * 8;
  f32x4 acc[4][4] = {};
  for (int k0 = 0; k0 < 512; k0 += 32){
    __syncthreads();
#pragma unroll
    for (int j = 0; j < 2; j++){
      const short* ga = X  + (size_t)(bm + j * 64 + r8) * 512 + (k0 + c8);
      const short* gb = Wt + (size_t)(bn + j * 64 + r8) * 512 + (k0 + c8);
      gload_lds16(ga, &Al[j * 2048 + w * 512]);
      gload_lds16(gb, &Bl[j * 2048 + w * 512]);
    }
    __syncthreads();
    s16x8 af[4], bv[4];
#pragma unroll
    for (int f = 0; f < 4; f++){
      af[f] = *(const s16x8*)(&Al[(wm + f * 16 + fr) * 32 + fg * 8]);
      bv[f] = *(const s16x8*)(&Bl[(wn + f * 16 + fr) * 32 + fg * 8]);
    }
#pragma unroll
    for (int i = 0; i < 4; i++)
#pragma unroll
      for (int jj = 0; jj < 4; jj++)
        acc[i][jj] = __builtin_amdgcn_mfma_f32_16x16x32_bf16(as_bf(af[i]), as_bf(bv[jj]),
                                                             acc[i][jj], 0, 0, 0);
  }
  const int row0 = bm + wm + fg * 4;
  const int col0 = bn + wn + fr;
#pragma unroll
  for (int i = 0; i < 4; i++)
#pragma unroll
    for (int jj = 0; jj < 4; jj++)
#pragma unroll
      for (int r = 0; r < 4; r++)
        C[(size_t)(row0 + i * 16 + r) * 512 + col0 + jj * 16] = acc[i][jj][r];
}

extern "C" void kernel_launch(void* const* d_in, const int* in_sizes, int n_in,
                              void* d_out, int out_size, void* d_ws, size_t ws_size,
                              hipStream_t stream){
  const float* query  = (const float*)d_in[0];
  const float* value  = (const float*)d_in[1];
  const float* key_in = (const float*)d_in[2];
  const float* Wq     = (const float*)d_in[3];
  const float* Wk     = (const float*)d_in[4];
  const float* Wv     = (const float*)d_in[5];
  const float* Wo     = (const float*)d_in[6];

  char* ws = (char*)d_ws;
  const size_t MB = 1ull << 20;
  short* Xq   = (short*)(ws);                    // 8 MB  (later reused as O)
  short* Xk   = (short*)(ws + 8 * MB);           // 8 MB
  short* Xv   = (short*)(ws + 16 * MB);          // 8 MB
  short* Wcat = (short*)(ws + 24 * MB);          // 2 MB: Wq,Wk,Wv,Wo transposed
  float* tab  = (float*)(ws + 26 * MB);          // 256 KB
  short* Qa   = (short*)(ws + 26 * MB + 256 * 1024);   // 8 MB
  short* Ka   = (short*)((char*)Qa + 8 * MB);          // 8 MB
  short* Va   = (short*)((char*)Ka + 8 * MB);          // 8 MB  (ends at 50.25 MB)
  short* Oa   = Xq;
  short* Wot  = Wcat + 786432;                   // Wo^T block

  k_conv3<<<dim3(4096, 1, 3), 256, 0, stream>>>(query, key_in, value, Xq);
  k_wt4<<<dim3(16, 16, 4), dim3(32, 8), 0, stream>>>(Wq, Wk, Wv, Wo, Wcat);
  k_table<<<128, 256, 0, stream>>>(tab);

  k_qkv<<<dim3(64, 12), 256, 0, stream>>>(Xq, Xk, Xv, Wcat, tab, Qa, Ka, Va);

  k_attn<<<2048, 128, 0, stream>>>(Qa, Ka, Va, Oa);

  k_gemm_out<<<dim3(64, 4), 256, 0, stream>>>(Oa, Wot, (float*)d_out);
}

// Round 7
// 95.626 us; speedup vs baseline: 1.5295x; 1.5295x over previous
//
#include <hip/hip_runtime.h>
#include <hip/hip_bf16.h>
#include <stdint.h>

#define DEV static __device__ __forceinline__

typedef __attribute__((ext_vector_type(8)))  short    s16x8;
typedef __attribute__((ext_vector_type(4)))  short    s16x4;
typedef __attribute__((ext_vector_type(8)))  __bf16   bf16x8;
typedef __attribute__((ext_vector_type(4)))  float    f32x4;
typedef __attribute__((ext_vector_type(16))) float    f32x16;
typedef __attribute__((ext_vector_type(2)))  unsigned u32x2;
typedef __attribute__((ext_vector_type(4)))  unsigned u32x4;

DEV short f2b(float f){           // round-to-nearest-even f32 -> bf16
  union{float f; uint32_t i;} x; x.f = f;
  uint32_t r = x.i + 0x7FFFu + ((x.i >> 16) & 1u);
  return (short)(r >> 16);
}
DEV bf16x8 as_bf(s16x8 v){ return __builtin_bit_cast(bf16x8, v); }
DEV float fexp2(float x){ return __builtin_amdgcn_exp2f(x); }   // v_exp_f32: 2^x
DEV f32x4 mf(s16x8 a, s16x8 b, f32x4 c){
  return __builtin_amdgcn_mfma_f32_16x16x32_bf16(as_bf(a), as_bf(b), c, 0, 0, 0);
}
DEV f32x16 mf32(s16x8 a, s16x8 b, f32x16 c){
  return __builtin_amdgcn_mfma_f32_32x32x16_bf16(as_bf(a), as_bf(b), c, 0, 0, 0);
}

DEV void gload_lds16(const void* g, void* l){
  __builtin_amdgcn_global_load_lds((const __attribute__((address_space(1))) void*)g,
                                   (__attribute__((address_space(3))) void*)l, 16, 0, 0);
}

// permlane32_swap: returns {x,y}: x = (a.lo | b.lo-as-hi), y = (a.hi-as-lo | b.hi)
#if __has_builtin(__builtin_amdgcn_permlane32_swap)
DEV void pswap2(unsigned a, unsigned b, unsigned& x, unsigned& y){
  u32x2 rr = __builtin_amdgcn_permlane32_swap(a, b, false, false);
  x = rr[0]; y = rr[1];
}
DEV float partner32(float v, int hi){
  unsigned u = __builtin_bit_cast(unsigned, v);
  u32x2 rr = __builtin_amdgcn_permlane32_swap(u, u, false, false);
  return __builtin_bit_cast(float, hi ? rr[0] : rr[1]);
}
#else
DEV void pswap2(unsigned a, unsigned b, unsigned& x, unsigned& y){
  unsigned pa_ = (unsigned)__shfl_xor((int)a, 32, 64);
  unsigned pb_ = (unsigned)__shfl_xor((int)b, 32, 64);
  int lo = ((threadIdx.x & 63) < 32);
  x = lo ? a   : pb_;
  y = lo ? pa_ : b;
}
DEV float partner32(float v, int hi){ (void)hi; return __shfl_xor(v, 32, 64); }
#endif

// ---------------- fused convert f32 -> bf16 for query/key_in/value ----------------
__global__ __launch_bounds__(256) void k_conv3(const float* __restrict__ q,
                                               const float* __restrict__ k,
                                               const float* __restrict__ v,
                                               short* __restrict__ out){
  int z = blockIdx.z;
  const float* in = (z == 0) ? q : (z == 1) ? k : v;
  int i = (blockIdx.x * 256 + threadIdx.x) * 4;
  float4 val = *(const float4*)(in + i);
  short o[4] = { f2b(val.x), f2b(val.y), f2b(val.z), f2b(val.w) };
  *(uint2*)(out + (size_t)z * 4194304 + i) = *(uint2*)o;
}

// ------------- fused weight transpose+convert: 4x w[512][512] f32 -> wt[n][k] bf16 -------------
__global__ __launch_bounds__(256) void k_wt4(const float* __restrict__ w0,
                                             const float* __restrict__ w1,
                                             const float* __restrict__ w2,
                                             const float* __restrict__ w3,
                                             short* __restrict__ wt){
  __shared__ float tile[32][33];
  int z = blockIdx.z;
  const float* w = (z == 0) ? w0 : (z == 1) ? w1 : (z == 2) ? w2 : w3;
  short* o = wt + (size_t)z * 262144;
  int bx = blockIdx.x * 32, by = blockIdx.y * 32;   // bx: n-block, by: k-block
  int tx = threadIdx.x, ty = threadIdx.y;           // (32, 8)
  for (int j = 0; j < 32; j += 8)
    tile[ty + j][tx] = w[(size_t)(by + ty + j) * 512 + bx + tx];
  __syncthreads();
  for (int j = 0; j < 32; j += 8)
    o[(size_t)(bx + ty + j) * 512 + by + tx] = f2b(tile[tx][ty + j]);
}

// ---------------- RoPE cos/sin table: tab[s][j][{cos,sin}], s<1024, j<32 ----------------
__global__ __launch_bounds__(256) void k_table(float* __restrict__ tab){
  int idx = blockIdx.x * 256 + threadIdx.x;   // 32768
  int s = idx >> 5, j = idx & 31;
  float inv = __expf(-(float)j * (1.0f / 32.0f) * logf(10000.0f));
  float ang = (float)s * inv;
  tab[idx * 2 + 0] = cosf(ang);
  tab[idx * 2 + 1] = sinf(ang);
}

// ---------------- fused QKV GEMM + RoPE/layout epilogues ----------------
__global__ __launch_bounds__(256) void k_qkv(const short* __restrict__ Xq,
                                             const short* __restrict__ Xk,
                                             const short* __restrict__ Xv,
                                             const short* __restrict__ Wcat,
                                             const float* __restrict__ tab,
                                             short* __restrict__ Qa,
                                             short* __restrict__ Ka,
                                             short* __restrict__ Vt){
  __shared__ __align__(16) short Al[128 * 32];
  __shared__ __align__(16) short Bl[128 * 32];
  const int t = threadIdx.x;
  const int w = t >> 6, lane = t & 63, fr = lane & 15, fg = lane >> 4;
  const int sel = blockIdx.y >> 2;
  const short* X = (sel == 0) ? Xq : (sel == 1) ? Xk : Xv;
  const int bm = blockIdx.x * 128, bn = blockIdx.y * 128;
  const int wm = (w >> 1) * 64, wn = (w & 1) * 64;
  const int r8 = t >> 2, c8 = (t & 3) * 8;
  f32x4 acc[4][4] = {};
  for (int k0 = 0; k0 < 512; k0 += 32){
    __syncthreads();
#pragma unroll
    for (int j = 0; j < 2; j++){
      const short* ga = X    + (size_t)(bm + j * 64 + r8) * 512 + (k0 + c8);
      const short* gb = Wcat + (size_t)(bn + j * 64 + r8) * 512 + (k0 + c8);
      gload_lds16(ga, &Al[j * 2048 + w * 512]);
      gload_lds16(gb, &Bl[j * 2048 + w * 512]);
    }
    __syncthreads();
    s16x8 af[4], bv[4];
#pragma unroll
    for (int f = 0; f < 4; f++){
      af[f] = *(const s16x8*)(&Al[(wm + f * 16 + fr) * 32 + fg * 8]);
      bv[f] = *(const s16x8*)(&Bl[(wn + f * 16 + fr) * 32 + fg * 8]);
    }
#pragma unroll
    for (int i = 0; i < 4; i++)
#pragma unroll
      for (int jj = 0; jj < 4; jj++)
        acc[i][jj] = __builtin_amdgcn_mfma_f32_16x16x32_bf16(as_bf(af[i]), as_bf(bv[jj]),
                                                             acc[i][jj], 0, 0, 0);
  }
  const int row0 = bm + wm + fg * 4;         // + i*16 + r
  const int b = row0 >> 10;
  const int s_base = row0 & 1023;
  const int hh = (((blockIdx.y & 3) * 128) + wn) >> 6;   // head 0..7
  if (sel < 2){
    const float scale = (sel == 0) ? 0.125f * 1.44269504f : 1.0f;
    short* out = (sel == 0) ? Qa : Ka;
#pragma unroll
    for (int i = 0; i < 4; i++)
#pragma unroll
      for (int jj = 0; jj < 2; jj++){
        int d = jj * 16 + fr;                // 0..31
#pragma unroll
        for (int r = 0; r < 4; r++){
          int s = s_base + i * 16 + r;
          float2 cs = *(const float2*)(tab + (size_t)(s * 32 + d) * 2);
          float x1 = acc[i][jj][r], x2 = acc[i][jj + 2][r];
          size_t ob = ((size_t)((b * 8 + hh) * 1024 + s)) * 64 + d;
          out[ob]      = f2b((x1 * cs.x - x2 * cs.y) * scale);
          out[ob + 32] = f2b((x2 * cs.x + x1 * cs.y) * scale);
        }
      }
  } else {
#pragma unroll
    for (int i = 0; i < 4; i++)
#pragma unroll
      for (int jj = 0; jj < 4; jj++){
        int d = jj * 16 + fr;
        s16x4 pk;
#pragma unroll
        for (int r = 0; r < 4; r++) pk[r] = f2b(acc[i][jj][r]);
        size_t ob = ((size_t)((b * 8 + hh) * 64 + d)) * 1024 + s_base + i * 16;
        *(s16x4*)(Vt + ob) = pk;
      }
  }
}

// ---------------- causal flash attention: 32x32 MFMA, in-register softmax ----------------
// Block = 128 thr (2 waves) owns 64 q rows [B0, B0+64); wave w takes rows B0+2c+w (c=0..31)
// so both waves share the causal kv range [0, B0+64). K and V^T chunks (64x64 bf16 each)
// are LDS-staged via global_load_lds with pre-swizzled source (slot ^= row&7), double-buffered.
// Swapped QK^T (mfma(K,Q)) puts a full q-row in-lane: softmax = reg-fmax + 1 permlane32_swap.
// P -> PV A-frags fully in-register via pack + permlane32_swap (T12). l via in-lane sum.
__global__ __launch_bounds__(128) void k_attn(const short* __restrict__ Qb,
                                              const short* __restrict__ Kb,
                                              const short* __restrict__ Vt,
                                              short* __restrict__ O){
  __shared__ __align__(16) short KL[2][4096];
  __shared__ __align__(16) short VL[2][4096];
  const int bid = blockIdx.x;
  // balanced heavy-first q-block order: every CU-round group of 4 sums to Bi-total 30
  const int podr[16] = {15,14,13,12, 0,1,2,3, 11,10,9,8, 4,5,6,7};
  const int Bi = podr[bid >> 6];
  const int bh = bid & 63;                   // bid%8 == bh%8 -> bh pinned to one XCD
  const int B0 = Bi * 64;
  const int t = threadIdx.x, w = t >> 6, lane = t & 63;
  const int col = lane & 31, hi = lane >> 5;
  const short* Qp = Qb + (size_t)bh * 65536;
  const short* Kp = Kb + (size_t)bh * 65536;
  const short* Vp = Vt + (size_t)bh * 65536;  // V^T: [64 d][1024 kv]
  const int qrow = B0 + 2 * col + w;          // this lane's q row (softmax axis)

  // Q B-frags: B[k=d][col=q] -> lane reads Q[qrow][ks*16 + hi*8 + j]
  s16x8 qb[4];
#pragma unroll
  for (int ks = 0; ks < 4; ks++)
    qb[ks] = *(const s16x8*)(Qp + (size_t)qrow * 64 + ks * 16 + hi * 8);

  int crow[16];
#pragma unroll
  for (int r = 0; r < 16; r++) crow[r] = (r & 3) + 8 * (r >> 2) + 4 * hi;

  f32x16 oacc[2] = {};                       // O[q(crow)][d = df*32 + col]
  float m = -1e30f, l = 0.f;

  auto stage = [&](int buf, int kv0){
#pragma unroll
    for (int R = 0; R < 4; R++){
      int lin = R * 128 + w * 64 + lane;     // 0..511 : row = lin/8, 16B-slot = lin%8
      int row = lin >> 3, slot = lin & 7;
      int gs = ((slot ^ (row & 7)) * 8);     // inverse-swizzled global source (rule #21)
      gload_lds16(Kp + (size_t)(kv0 + row) * 64 + gs, &KL[buf][(R * 128 + w * 64) * 8]);
      gload_lds16(Vp + (size_t)row * 1024 + kv0 + gs, &VL[buf][(R * 128 + w * 64) * 8]);
    }
  };

  stage(0, 0);
  __syncthreads();

  int cur = 0;
  for (int kv0 = 0; kv0 <= B0; kv0 += 64){
    if (kv0 < B0) stage(cur ^ 1, kv0 + 64);  // issue next-chunk loads before compute
    // ---- QK^T (swapped): D[kv][q], A = K chunk, B = Q ----
    f32x16 sc[2];
#pragma unroll
    for (int f = 0; f < 2; f++){
      f32x16 s = {};
      int row = f * 32 + col, rx = row & 7;
#pragma unroll
      for (int ks = 0; ks < 4; ks++){
        s16x8 ka = *(const s16x8*)(&KL[cur][row * 64 + ((ks * 2 + hi) ^ rx) * 8]);
        s = mf32(ka, qb[ks], s);
      }
      sc[f] = s;
    }
    // ---- causal mask (last chunk only) ----
    if (kv0 == B0){
#pragma unroll
      for (int f = 0; f < 2; f++)
#pragma unroll
        for (int r = 0; r < 16; r++){
          int kv = kv0 + f * 32 + crow[r];
          if (kv > qrow) sc[f][r] = -1e30f;
        }
    }
    // ---- softmax: in-lane 31 fmax + 1 permlane; defer-max rescale ----
    float tm = -1e30f;
#pragma unroll
    for (int f = 0; f < 2; f++)
#pragma unroll
      for (int r = 0; r < 16; r++) tm = fmaxf(tm, sc[f][r]);
    tm = fmaxf(tm, partner32(tm, hi));
    if (!__all(tm <= m + 8.f)){
      float mn = fmaxf(m, tm);
      float corr = fexp2(m - mn);
      m = mn;
      l *= corr;
      float cpv[16];
#pragma unroll
      for (int r = 0; r < 16; r++) cpv[r] = __shfl(corr, crow[r], 64);
#pragma unroll
      for (int r = 0; r < 16; r++){ oacc[0][r] *= cpv[r]; oacc[1][r] *= cpv[r]; }
    }
    float rs = 0.f;
    unsigned wq[2][8];
#pragma unroll
    for (int f = 0; f < 2; f++)
#pragma unroll
      for (int i = 0; i < 8; i++){
        float p0 = fexp2(sc[f][2 * i]     - m);
        float p1 = fexp2(sc[f][2 * i + 1] - m);
        rs += p0 + p1;
        wq[f][i] = (unsigned)(uint16_t)f2b(p0) | ((unsigned)(uint16_t)f2b(p1) << 16);
      }
    rs += partner32(rs, hi);
    l += rs;
    // ---- P words -> PV A-frags via permlane32_swap (no LDS) ----
    s16x8 pa[4];
#pragma unroll
    for (int f = 0; f < 2; f++)
#pragma unroll
      for (int half = 0; half < 2; half++){
        unsigned w0, w1, w2, w3;
        pswap2(wq[f][half * 4 + 0], wq[f][half * 4 + 2], w0, w2);
        pswap2(wq[f][half * 4 + 1], wq[f][half * 4 + 3], w1, w3);
        u32x4 uv = { w0, w1, w2, w3 };
        pa[f * 2 + half] = __builtin_bit_cast(s16x8, uv);
      }
    // ---- PV: O += P V, B = V^T chunk ----
#pragma unroll
    for (int ks = 0; ks < 4; ks++)
#pragma unroll
      for (int df = 0; df < 2; df++){
        int row = df * 32 + col;
        s16x8 vb = *(const s16x8*)(&VL[cur][row * 64 + ((ks * 2 + hi) ^ (row & 7)) * 8]);
        oacc[df] = mf32(pa[ks], vb, oacc[df]);
      }
    if (kv0 < B0) __syncthreads();           // drains stage loads (vmcnt) + protects buffers
    cur ^= 1;
  }

  // ---- normalize + store ----
  const int b = bh >> 3, h = bh & 7;
  float lf[16];
#pragma unroll
  for (int r = 0; r < 16; r++) lf[r] = __shfl(l, crow[r], 64);
#pragma unroll
  for (int r = 0; r < 16; r++){
    int qq = B0 + 2 * crow[r] + w;
    float inv = 1.0f / lf[r];
    O[(size_t)(b * 1024 + qq) * 512 + h * 64 + col]      = f2b(oacc[0][r] * inv);
    O[(size_t)(b * 1024 + qq) * 512 + h * 64 + 32 + col] = f2b(oacc[1][r] * inv);
  }
}

// ---------------- final GEMM: f32 out ----------------
__global__ __launch_bounds__(256) void k_gemm_out(const short* __restrict__ X,
                                                  const short* __restrict__ Wt,
                                                  float* __restrict__ C){
  __shared__ __align__(16) short Al[128 * 32];
  __shared__ __align__(16) short Bl[128 * 32];
  const int t = threadIdx.x;
  const int w = t >> 6, lane = t & 63, fr = lane & 15, fg = lane >> 4;
  const int bm = blockIdx.x * 128, bn = blockIdx.y * 128;
  const int wm = (w >> 1) * 64, wn = (w & 1) * 64;
  const int r8 = t >> 2, c8 = (t & 3) * 8;
  f32x4 acc[4][4] = {};
  for (int k0 = 0; k0 < 512; k0 += 32){
    __syncthreads();
#pragma unroll
    for (int j = 0; j < 2; j++){
      const short* ga = X  + (size_t)(bm + j * 64 + r8) * 512 + (k0 + c8);
      const short* gb = Wt + (size_t)(bn + j * 64 + r8) * 512 + (k0 + c8);
      gload_lds16(ga, &Al[j * 2048 + w * 512]);
      gload_lds16(gb, &Bl[j * 2048 + w * 512]);
    }
    __syncthreads();
    s16x8 af[4], bv[4];
#pragma unroll
    for (int f = 0; f < 4; f++){
      af[f] = *(const s16x8*)(&Al[(wm + f * 16 + fr) * 32 + fg * 8]);
      bv[f] = *(const s16x8*)(&Bl[(wn + f * 16 + fr) * 32 + fg * 8]);
    }
#pragma unroll
    for (int i = 0; i < 4; i++)
#pragma unroll
      for (int jj = 0; jj < 4; jj++)
        acc[i][jj] = __builtin_amdgcn_mfma_f32_16x16x32_bf16(as_bf(af[i]), as_bf(bv[jj]),
                                                             acc[i][jj], 0, 0, 0);
  }
  const int row0 = bm + wm + fg * 4;
  const int col0 = bn + wn + fr;
#pragma unroll
  for (int i = 0; i < 4; i++)
#pragma unroll
    for (int jj = 0; jj < 4; jj++)
#pragma unroll
      for (int r = 0; r < 4; r++)
        C[(size_t)(row0 + i * 16 + r) * 512 + col0 + jj * 16] = acc[i][jj][r];
}

extern "C" void kernel_launch(void* const* d_in, const int* in_sizes, int n_in,
                              void* d_out, int out_size, void* d_ws, size_t ws_size,
                              hipStream_t stream){
  const float* query  = (const float*)d_in[0];
  const float* value  = (const float*)d_in[1];
  const float* key_in = (const float*)d_in[2];
  const float* Wq     = (const float*)d_in[3];
  const float* Wk     = (const float*)d_in[4];
  const float* Wv     = (const float*)d_in[5];
  const float* Wo     = (const float*)d_in[6];

  char* ws = (char*)d_ws;
  const size_t MB = 1ull << 20;
  short* Xq   = (short*)(ws);                    // 8 MB  (later reused as O)
  short* Xk   = (short*)(ws + 8 * MB);           // 8 MB
  short* Xv   = (short*)(ws + 16 * MB);          // 8 MB
  short* Wcat = (short*)(ws + 24 * MB);          // 2 MB: Wq,Wk,Wv,Wo transposed
  float* tab  = (float*)(ws + 26 * MB);          // 256 KB
  short* Qa   = (short*)(ws + 26 * MB + 256 * 1024);   // 8 MB
  short* Ka   = (short*)((char*)Qa + 8 * MB);          // 8 MB
  short* Va   = (short*)((char*)Ka + 8 * MB);          // 8 MB  (ends at 50.25 MB)
  short* Oa   = Xq;
  short* Wot  = Wcat + 786432;                   // Wo^T block

  k_conv3<<<dim3(4096, 1, 3), 256, 0, stream>>>(query, key_in, value, Xq);
  k_wt4<<<dim3(16, 16, 4), dim3(32, 8), 0, stream>>>(Wq, Wk, Wv, Wo, Wcat);
  k_table<<<128, 256, 0, stream>>>(tab);

  k_qkv<<<dim3(64, 12), 256, 0, stream>>>(Xq, Xk, Xv, Wcat, tab, Qa, Ka, Va);

  k_attn<<<1024, 128, 0, stream>>>(Qa, Ka, Va, Oa);

  k_gemm_out<<<dim3(64, 4), 256, 0, stream>>>(Oa, Wot, (float*)d_out);
}

// Round 8
// 78.781 us; speedup vs baseline: 1.8565x; 1.2138x over previous
//
#include <hip/hip_runtime.h>
#include <hip/hip_bf16.h>
#include <stdint.h>

#define DEV static __device__ __forceinline__

typedef __attribute__((ext_vector_type(8)))  short    s16x8;
typedef __attribute__((ext_vector_type(4)))  short    s16x4;
typedef __attribute__((ext_vector_type(8)))  __bf16   bf16x8;
typedef __attribute__((ext_vector_type(4)))  float    f32x4;
typedef __attribute__((ext_vector_type(16))) float    f32x16;
typedef __attribute__((ext_vector_type(2)))  unsigned u32x2;
typedef __attribute__((ext_vector_type(4)))  unsigned u32x4;

DEV short f2b(float f){           // round-to-nearest-even f32 -> bf16
  union{float f; uint32_t i;} x; x.f = f;
  uint32_t r = x.i + 0x7FFFu + ((x.i >> 16) & 1u);
  return (short)(r >> 16);
}
DEV bf16x8 as_bf(s16x8 v){ return __builtin_bit_cast(bf16x8, v); }
DEV float fexp2(float x){ return __builtin_amdgcn_exp2f(x); }   // v_exp_f32: 2^x
DEV f32x4 mf(s16x8 a, s16x8 b, f32x4 c){
  return __builtin_amdgcn_mfma_f32_16x16x32_bf16(as_bf(a), as_bf(b), c, 0, 0, 0);
}
DEV f32x16 mf32(s16x8 a, s16x8 b, f32x16 c){
  return __builtin_amdgcn_mfma_f32_32x32x16_bf16(as_bf(a), as_bf(b), c, 0, 0, 0);
}

DEV void gload_lds16(const void* g, void* l){
  __builtin_amdgcn_global_load_lds((const __attribute__((address_space(1))) void*)g,
                                   (__attribute__((address_space(3))) void*)l, 16, 0, 0);
}

#if __has_builtin(__builtin_amdgcn_permlane32_swap)
DEV void pswap2(unsigned a, unsigned b, unsigned& x, unsigned& y){
  u32x2 rr = __builtin_amdgcn_permlane32_swap(a, b, false, false);
  x = rr[0]; y = rr[1];
}
DEV float partner32(float v, int hi){
  unsigned u = __builtin_bit_cast(unsigned, v);
  u32x2 rr = __builtin_amdgcn_permlane32_swap(u, u, false, false);
  return __builtin_bit_cast(float, hi ? rr[0] : rr[1]);
}
#else
DEV void pswap2(unsigned a, unsigned b, unsigned& x, unsigned& y){
  unsigned pa_ = (unsigned)__shfl_xor((int)a, 32, 64);
  unsigned pb_ = (unsigned)__shfl_xor((int)b, 32, 64);
  int lo = ((threadIdx.x & 63) < 32);
  x = lo ? a   : pb_;
  y = lo ? pa_ : b;
}
DEV float partner32(float v, int hi){ (void)hi; return __shfl_xor(v, 32, 64); }
#endif

// ------------- fused weight transpose+convert: 4x w[512][512] f32 -> wt[n][k] bf16 -------------
__global__ __launch_bounds__(256) void k_wt4(const float* __restrict__ w0,
                                             const float* __restrict__ w1,
                                             const float* __restrict__ w2,
                                             const float* __restrict__ w3,
                                             short* __restrict__ wt){
  __shared__ float tile[32][33];
  int z = blockIdx.z;
  const float* w = (z == 0) ? w0 : (z == 1) ? w1 : (z == 2) ? w2 : w3;
  short* o = wt + (size_t)z * 262144;
  int bx = blockIdx.x * 32, by = blockIdx.y * 32;   // bx: n-block, by: k-block
  int tx = threadIdx.x, ty = threadIdx.y;           // (32, 8)
  for (int j = 0; j < 32; j += 8)
    tile[ty + j][tx] = w[(size_t)(by + ty + j) * 512 + bx + tx];
  __syncthreads();
  for (int j = 0; j < 32; j += 8)
    o[(size_t)(bx + ty + j) * 512 + by + tx] = f2b(tile[tx][ty + j]);
}

// ---------------- RoPE cos/sin table: tab[s][j][{cos,sin}], s<1024, j<32 ----------------
__global__ __launch_bounds__(256) void k_table(float* __restrict__ tab){
  int idx = blockIdx.x * 256 + threadIdx.x;   // 32768
  int s = idx >> 5, j = idx & 31;
  float inv = __expf(-(float)j * (1.0f / 32.0f) * logf(10000.0f));
  float ang = (float)s * inv;
  tab[idx * 2 + 0] = cosf(ang);
  tab[idx * 2 + 1] = sinf(ang);
}

// ---------------- fused convert + QKV GEMM + RoPE/layout epilogues ----------------
// A (f32 input) reg-staged with cvt->ds_write; B (bf16 Wcat) via global_load_lds.
// 2-phase double-buffer: one barrier per K-step; stage(t+1) issued before compute(t).
__global__ __launch_bounds__(256) void k_qkv(const float* __restrict__ Xq,
                                             const float* __restrict__ Xk,
                                             const float* __restrict__ Xv,
                                             const short* __restrict__ Wcat,
                                             const float* __restrict__ tab,
                                             short* __restrict__ Qa,
                                             short* __restrict__ Ka,
                                             short* __restrict__ Vt){
  __shared__ __align__(16) short Al[2][128 * 32];
  __shared__ __align__(16) short Bl[2][128 * 32];
  const int t = threadIdx.x;
  const int w = t >> 6, lane = t & 63, fr = lane & 15, fg = lane >> 4;
  const int sel = blockIdx.y >> 2;
  const float* X = (sel == 0) ? Xq : (sel == 1) ? Xk : Xv;
  const int bm = blockIdx.x * 128, bn = blockIdx.y * 128;
  const int wm = (w >> 1) * 64, wn = (w & 1) * 64;
  const int r8 = t >> 2, c8 = (t & 3) * 8;

  float4 ua[4];                              // in-flight A f32 (issue-early, write-late)
  auto ldA = [&](int k0){
    const float* s0 = X + (size_t)(bm + (t >> 2)) * 512 + k0 + c8;
    const float* s1 = s0 + 64 * 512;
    ua[0] = *(const float4*)(s0);
    ua[1] = *(const float4*)(s0 + 4);
    ua[2] = *(const float4*)(s1);
    ua[3] = *(const float4*)(s1 + 4);
  };
  auto wrA = [&](int buf){
    s16x8 p0 = { f2b(ua[0].x), f2b(ua[0].y), f2b(ua[0].z), f2b(ua[0].w),
                 f2b(ua[1].x), f2b(ua[1].y), f2b(ua[1].z), f2b(ua[1].w) };
    s16x8 p1 = { f2b(ua[2].x), f2b(ua[2].y), f2b(ua[2].z), f2b(ua[2].w),
                 f2b(ua[3].x), f2b(ua[3].y), f2b(ua[3].z), f2b(ua[3].w) };
    *(s16x8*)(&Al[buf][(t >> 2) * 32 + c8])        = p0;
    *(s16x8*)(&Al[buf][(64 + (t >> 2)) * 32 + c8]) = p1;
  };
  auto stB = [&](int buf, int k0){
#pragma unroll
    for (int j = 0; j < 2; j++)
      gload_lds16(Wcat + (size_t)(bn + j * 64 + r8) * 512 + k0 + c8,
                  &Bl[buf][j * 2048 + w * 512]);
  };

  f32x4 acc[4][4] = {};
  ldA(0); stB(0, 0); wrA(0);
  __syncthreads();
  int cur = 0;
  for (int t16 = 0; t16 < 16; ++t16){
    const int k0n = (t16 + 1) * 32;
    if (t16 < 15){ ldA(k0n); stB(cur ^ 1, k0n); }
    s16x8 af[4], bv[4];
#pragma unroll
    for (int f = 0; f < 4; f++){
      af[f] = *(const s16x8*)(&Al[cur][(wm + f * 16 + fr) * 32 + fg * 8]);
      bv[f] = *(const s16x8*)(&Bl[cur][(wn + f * 16 + fr) * 32 + fg * 8]);
    }
#pragma unroll
    for (int i = 0; i < 4; i++)
#pragma unroll
      for (int jj = 0; jj < 4; jj++)
        acc[i][jj] = mf(af[i], bv[jj], acc[i][jj]);
    if (t16 < 15) wrA(cur ^ 1);
    __syncthreads();
    cur ^= 1;
  }

  const int row0 = bm + wm + fg * 4;         // + i*16 + r
  const int b = row0 >> 10;
  const int s_base = row0 & 1023;
  const int hh = (((blockIdx.y & 3) * 128) + wn) >> 6;   // head 0..7
  if (sel < 2){
    const float scale = (sel == 0) ? 0.125f * 1.44269504f : 1.0f;
    short* out = (sel == 0) ? Qa : Ka;
#pragma unroll
    for (int i = 0; i < 4; i++)
#pragma unroll
      for (int jj = 0; jj < 2; jj++){
        int d = jj * 16 + fr;                // 0..31
#pragma unroll
        for (int r = 0; r < 4; r++){
          int s = s_base + i * 16 + r;
          float2 cs = *(const float2*)(tab + (size_t)(s * 32 + d) * 2);
          float x1 = acc[i][jj][r], x2 = acc[i][jj + 2][r];
          size_t ob = ((size_t)((b * 8 + hh) * 1024 + s)) * 64 + d;
          out[ob]      = f2b((x1 * cs.x - x2 * cs.y) * scale);
          out[ob + 32] = f2b((x2 * cs.x + x1 * cs.y) * scale);
        }
      }
  } else {
#pragma unroll
    for (int i = 0; i < 4; i++)
#pragma unroll
      for (int jj = 0; jj < 4; jj++){
        int d = jj * 16 + fr;
        s16x4 pk;
#pragma unroll
        for (int r = 0; r < 4; r++) pk[r] = f2b(acc[i][jj][r]);
        size_t ob = ((size_t)((b * 8 + hh) * 64 + d)) * 1024 + s_base + i * 16;
        *(s16x4*)(Vt + ob) = pk;
      }
  }
}

// ---------------- causal flash attention: 32x32 MFMA, in-register softmax ----------------
__global__ __launch_bounds__(128) void k_attn(const short* __restrict__ Qb,
                                              const short* __restrict__ Kb,
                                              const short* __restrict__ Vt,
                                              short* __restrict__ O){
  __shared__ __align__(16) short KL[2][4096];
  __shared__ __align__(16) short VL[2][4096];
  const int bid = blockIdx.x;
  const int podr[16] = {15,14,13,12, 0,1,2,3, 11,10,9,8, 4,5,6,7};
  const int Bi = podr[bid >> 6];
  const int bh = bid & 63;                   // bid%8 == bh%8 -> bh pinned to one XCD
  const int B0 = Bi * 64;
  const int t = threadIdx.x, w = t >> 6, lane = t & 63;
  const int col = lane & 31, hi = lane >> 5;
  const short* Qp = Qb + (size_t)bh * 65536;
  const short* Kp = Kb + (size_t)bh * 65536;
  const short* Vp = Vt + (size_t)bh * 65536;  // V^T: [64 d][1024 kv]
  const int qrow = B0 + 2 * col + w;          // this lane's q row (softmax axis)

  s16x8 qb[4];
#pragma unroll
  for (int ks = 0; ks < 4; ks++)
    qb[ks] = *(const s16x8*)(Qp + (size_t)qrow * 64 + ks * 16 + hi * 8);

  int crow[16];
#pragma unroll
  for (int r = 0; r < 16; r++) crow[r] = (r & 3) + 8 * (r >> 2) + 4 * hi;

  f32x16 oacc[2] = {};                       // O[q(crow)][d = df*32 + col]
  float m = -1e30f, l = 0.f;

  auto stage = [&](int buf, int kv0){
#pragma unroll
    for (int R = 0; R < 4; R++){
      int lin = R * 128 + w * 64 + lane;     // 0..511 : row = lin/8, 16B-slot = lin%8
      int row = lin >> 3, slot = lin & 7;
      int gs = ((slot ^ (row & 7)) * 8);     // inverse-swizzled global source (rule #21)
      gload_lds16(Kp + (size_t)(kv0 + row) * 64 + gs, &KL[buf][(R * 128 + w * 64) * 8]);
      gload_lds16(Vp + (size_t)row * 1024 + kv0 + gs, &VL[buf][(R * 128 + w * 64) * 8]);
    }
  };

  stage(0, 0);
  __syncthreads();

  int cur = 0;
  for (int kv0 = 0; kv0 <= B0; kv0 += 64){
    if (kv0 < B0) stage(cur ^ 1, kv0 + 64);  // issue next-chunk loads before compute
    f32x16 sc[2];
#pragma unroll
    for (int f = 0; f < 2; f++){
      f32x16 s = {};
      int row = f * 32 + col, rx = row & 7;
#pragma unroll
      for (int ks = 0; ks < 4; ks++){
        s16x8 ka = *(const s16x8*)(&KL[cur][row * 64 + ((ks * 2 + hi) ^ rx) * 8]);
        s = mf32(ka, qb[ks], s);
      }
      sc[f] = s;
    }
    if (kv0 == B0){
#pragma unroll
      for (int f = 0; f < 2; f++)
#pragma unroll
        for (int r = 0; r < 16; r++){
          int kv = kv0 + f * 32 + crow[r];
          if (kv > qrow) sc[f][r] = -1e30f;
        }
    }
    float tm = -1e30f;
#pragma unroll
    for (int f = 0; f < 2; f++)
#pragma unroll
      for (int r = 0; r < 16; r++) tm = fmaxf(tm, sc[f][r]);
    tm = fmaxf(tm, partner32(tm, hi));
    if (!__all(tm <= m + 8.f)){
      float mn = fmaxf(m, tm);
      float corr = fexp2(m - mn);
      m = mn;
      l *= corr;
      float cpv[16];
#pragma unroll
      for (int r = 0; r < 16; r++) cpv[r] = __shfl(corr, crow[r], 64);
#pragma unroll
      for (int r = 0; r < 16; r++){ oacc[0][r] *= cpv[r]; oacc[1][r] *= cpv[r]; }
    }
    float rs = 0.f;
    unsigned wq[2][8];
#pragma unroll
    for (int f = 0; f < 2; f++)
#pragma unroll
      for (int i = 0; i < 8; i++){
        float p0 = fexp2(sc[f][2 * i]     - m);
        float p1 = fexp2(sc[f][2 * i + 1] - m);
        rs += p0 + p1;
        wq[f][i] = (unsigned)(uint16_t)f2b(p0) | ((unsigned)(uint16_t)f2b(p1) << 16);
      }
    rs += partner32(rs, hi);
    l += rs;
    s16x8 pa[4];
#pragma unroll
    for (int f = 0; f < 2; f++)
#pragma unroll
      for (int half = 0; half < 2; half++){
        unsigned w0, w1, w2, w3;
        pswap2(wq[f][half * 4 + 0], wq[f][half * 4 + 2], w0, w2);
        pswap2(wq[f][half * 4 + 1], wq[f][half * 4 + 3], w1, w3);
        u32x4 uv = { w0, w1, w2, w3 };
        pa[f * 2 + half] = __builtin_bit_cast(s16x8, uv);
      }
#pragma unroll
    for (int ks = 0; ks < 4; ks++)
#pragma unroll
      for (int df = 0; df < 2; df++){
        int row = df * 32 + col;
        s16x8 vb = *(const s16x8*)(&VL[cur][row * 64 + ((ks * 2 + hi) ^ (row & 7)) * 8]);
        oacc[df] = mf32(pa[ks], vb, oacc[df]);
      }
    if (kv0 < B0) __syncthreads();           // drains stage loads (vmcnt) + protects buffers
    cur ^= 1;
  }

  const int b = bh >> 3, h = bh & 7;
  float lf[16];
#pragma unroll
  for (int r = 0; r < 16; r++) lf[r] = __shfl(l, crow[r], 64);
#pragma unroll
  for (int r = 0; r < 16; r++){
    int qq = B0 + 2 * crow[r] + w;
    float inv = 1.0f / lf[r];
    O[(size_t)(b * 1024 + qq) * 512 + h * 64 + col]      = f2b(oacc[0][r] * inv);
    O[(size_t)(b * 1024 + qq) * 512 + h * 64 + 32 + col] = f2b(oacc[1][r] * inv);
  }
}

// ---------------- final GEMM (2-phase dbuf): f32 out ----------------
__global__ __launch_bounds__(256) void k_gemm_out(const short* __restrict__ X,
                                                  const short* __restrict__ Wt,
                                                  float* __restrict__ C){
  __shared__ __align__(16) short Al[2][128 * 32];
  __shared__ __align__(16) short Bl[2][128 * 32];
  const int t = threadIdx.x;
  const int w = t >> 6, lane = t & 63, fr = lane & 15, fg = lane >> 4;
  const int bm = blockIdx.x * 128, bn = blockIdx.y * 128;
  const int wm = (w >> 1) * 64, wn = (w & 1) * 64;
  const int r8 = t >> 2, c8 = (t & 3) * 8;

  auto stage = [&](int buf, int k0){
#pragma unroll
    for (int j = 0; j < 2; j++){
      gload_lds16(X  + (size_t)(bm + j * 64 + r8) * 512 + k0 + c8, &Al[buf][j * 2048 + w * 512]);
      gload_lds16(Wt + (size_t)(bn + j * 64 + r8) * 512 + k0 + c8, &Bl[buf][j * 2048 + w * 512]);
    }
  };

  f32x4 acc[4][4] = {};
  stage(0, 0);
  __syncthreads();
  int cur = 0;
  for (int t16 = 0; t16 < 16; ++t16){
    if (t16 < 15) stage(cur ^ 1, (t16 + 1) * 32);
    s16x8 af[4], bv[4];
#pragma unroll
    for (int f = 0; f < 4; f++){
      af[f] = *(const s16x8*)(&Al[cur][(wm + f * 16 + fr) * 32 + fg * 8]);
      bv[f] = *(const s16x8*)(&Bl[cur][(wn + f * 16 + fr) * 32 + fg * 8]);
    }
#pragma unroll
    for (int i = 0; i < 4; i++)
#pragma unroll
      for (int jj = 0; jj < 4; jj++)
        acc[i][jj] = mf(af[i], bv[jj], acc[i][jj]);
    __syncthreads();
    cur ^= 1;
  }
  const int row0 = bm + wm + fg * 4;
  const int col0 = bn + wn + fr;
#pragma unroll
  for (int i = 0; i < 4; i++)
#pragma unroll
    for (int jj = 0; jj < 4; jj++)
#pragma unroll
      for (int r = 0; r < 4; r++)
        C[(size_t)(row0 + i * 16 + r) * 512 + col0 + jj * 16] = acc[i][jj][r];
}

extern "C" void kernel_launch(void* const* d_in, const int* in_sizes, int n_in,
                              void* d_out, int out_size, void* d_ws, size_t ws_size,
                              hipStream_t stream){
  const float* query  = (const float*)d_in[0];
  const float* value  = (const float*)d_in[1];
  const float* key_in = (const float*)d_in[2];
  const float* Wq     = (const float*)d_in[3];
  const float* Wk     = (const float*)d_in[4];
  const float* Wv     = (const float*)d_in[5];
  const float* Wo     = (const float*)d_in[6];

  char* ws = (char*)d_ws;
  const size_t MB = 1ull << 20;
  short* Oa   = (short*)(ws);                    // 8 MB attention output
  short* Wcat = (short*)(ws + 24 * MB);          // 2 MB: Wq,Wk,Wv,Wo transposed
  float* tab  = (float*)(ws + 26 * MB);          // 256 KB
  short* Qa   = (short*)(ws + 26 * MB + 256 * 1024);   // 8 MB
  short* Ka   = (short*)((char*)Qa + 8 * MB);          // 8 MB
  short* Va   = (short*)((char*)Ka + 8 * MB);          // 8 MB  (ends at 50.25 MB)
  short* Wot  = Wcat + 786432;                   // Wo^T block

  k_wt4<<<dim3(16, 16, 4), dim3(32, 8), 0, stream>>>(Wq, Wk, Wv, Wo, Wcat);
  k_table<<<128, 256, 0, stream>>>(tab);

  k_qkv<<<dim3(64, 12), 256, 0, stream>>>(query, key_in, value, Wcat, tab, Qa, Ka, Va);

  k_attn<<<1024, 128, 0, stream>>>(Qa, Ka, Va, Oa);

  k_gemm_out<<<dim3(64, 4), 256, 0, stream>>>(Oa, Wot, (float*)d_out);
}